// Round 12
// baseline (142.171 us; speedup 1.0000x reference)
//
#include <hip/hip_runtime.h>

typedef _Float16 f16x8 __attribute__((ext_vector_type(8)));
typedef float    f32x4 __attribute__((ext_vector_type(4)));

#define CC 64
#define HWSZ 4096
#define CHWSZ 262144
#define NE 512
#define NPIX 131072
#define PIXB 128
#define NSTRIPE 32
#define XROW 144                 // padded x-tile row bytes (16B-aligned, 4-bank rotate)

#define ET_OFF 0                 // 512 codes * 128 B f16, XOR-swizzled rows = 65536
#define E2_OFF 65536             // 512 * 4 (exact)
#define MAXE2_OFF 67584          // 8 floats (per-init-block e2 max)
#define HIST_OFF 67712           // 32 * 512 * 4 = 65536
#define BATCH_OFF 133248         // 32 * 4
#define F2_OFF 133376            // 131072 * 4
#define PART_OFF 657664          // 131072 * 4 * 8 B

__device__ __forceinline__ unsigned short f16b(float f) {
    _Float16 h = (_Float16)f;                     // v_cvt_f16_f32, RN
    return __builtin_bit_cast(unsigned short, h);
}
__device__ __forceinline__ unsigned umin_(unsigned a, unsigned b) { return a < b ? a : b; }
__device__ __forceinline__ unsigned umax_(unsigned a, unsigned b) { return a > b ? a : b; }
__device__ __forceinline__ void gload16(const void* g, void* l) {
    __builtin_amdgcn_global_load_lds(
        (const __attribute__((address_space(1))) unsigned int*)g,
        (__attribute__((address_space(3))) unsigned int*)l, 16, 0, 0);
}

// ---- init (8 blocks): exact e2; f16 embed^T [code][k] swizzled; per-block e2max; zero hist ----
__global__ __launch_bounds__(512) void vq_init(const float* __restrict__ eg, char* __restrict__ ws) {
    __shared__ float smax[64];
    const int tid = threadIdx.x, blk = blockIdx.x;
    if (tid < 64) {
        int n = blk * 64 + tid;
        float s = 0.f;
        #pragma unroll 8
        for (int k = 0; k < CC; ++k) { float v = eg[k * NE + n]; s = __fadd_rn(s, __fmul_rn(v, v)); }
        ((float*)(ws + E2_OFF))[n] = s;
        smax[tid] = s;
    }
    char* et = ws + ET_OFF;
    #pragma unroll
    for (int it = 0; it < 4; ++it) {
        int idx = blk * 2048 + it * 512 + tid;    // word index, 32 words/code row
        int n = idx >> 5, w = idx & 31;
        float v0 = eg[(2 * w) * NE + n], v1 = eg[(2 * w + 1) * NE + n];
        unsigned int word = (unsigned int)f16b(v0) | ((unsigned int)f16b(v1) << 16);
        int b = n * 128 + ((w * 4) ^ ((n & 7) << 4));
        *(unsigned int*)(et + b) = word;
    }
    unsigned int* h32 = (unsigned int*)(ws + HIST_OFF);
    for (int i = blk * 2048 + tid; i < (blk + 1) * 2048; i += 512) h32[i] = 0u;
    __syncthreads();
    if (tid == 0) {
        float m = 0.f;
        for (int i = 0; i < 64; ++i) m = fmaxf(m, smax[i]);
        ((float*)(ws + MAXE2_OFF))[blk] = m;
    }
    if (blk == 0 && tid < 32) ((float*)(ws + BATCH_OFF))[tid] = 0.f;
}

// ---- K1: f16 single-pass screen, code-quarter split, packed-key argmin, one barrier ----
__global__ __launch_bounds__(256) void vq_screen(const float* __restrict__ xg,
                                                 char* __restrict__ ws) {
    __shared__ __align__(16) char xtb[PIXB * XROW];   // [pixel][k] f16, padded rows
    __shared__ __align__(16) char btb[16384];         // 128 codes x 128 B, swizzled
    __shared__ float e2q[128];
    __shared__ float f2h[2][PIXB];

    const int tid  = threadIdx.x;
    const int lane = tid & 63;
    const int wv   = tid >> 6;
    const int l15  = lane & 15;
    const int l4   = lane >> 4;
    const int blk  = blockIdx.x;
    const int tile = blk >> 2;
    const int q    = blk & 3;
    const int pix0 = tile * PIXB;
    const int bb   = pix0 >> 12;
    const size_t xbase = (size_t)bb * CHWSZ + (pix0 & 4095);

    // stage B quarter (pre-swizzled in ws; linear 1:1 copy)
    #pragma unroll
    for (int i = 0; i < 4; ++i)
        gload16(ws + ET_OFF + (size_t)q * 16384 + i * 4096 + tid * 16, &btb[i * 4096 + tid * 16]);

    // stage x tile as f16 (RN), padded rows; accumulate f2 partial
    {
        const int p = tid & 127, h = tid >> 7;
        float s = 0.f;
        #pragma unroll
        for (int qq = 0; qq < 4; ++qq) {
            int k0 = h * 32 + qq * 8;
            float v[8];
            #pragma unroll
            for (int j = 0; j < 8; ++j) v[j] = xg[xbase + (size_t)(k0 + j) * HWSZ + p];
            unsigned int w_[4];
            #pragma unroll
            for (int j = 0; j < 4; ++j) {
                w_[j] = (unsigned int)f16b(v[2 * j]) | ((unsigned int)f16b(v[2 * j + 1]) << 16);
                s = __fmaf_rn(v[2 * j], v[2 * j], s);
                s = __fmaf_rn(v[2 * j + 1], v[2 * j + 1], s);
            }
            *(uint4*)(xtb + p * XROW + h * 64 + qq * 16) = (uint4){w_[0], w_[1], w_[2], w_[3]};
        }
        f2h[h][p] = s;
        if (tid < 128) e2q[tid] = ((const float*)(ws + E2_OFF))[q * 128 + tid] + 512.f;
    }
    asm volatile("s_waitcnt vmcnt(0) lgkmcnt(0)" ::: "memory");
    __syncthreads();       // the ONLY barrier

    // A fragments: wave owns pixels [32wv, 32wv+32) = 2 m-tiles
    f16x8 a[2][2];
    #pragma unroll
    for (int mt = 0; mt < 2; ++mt) {
        int prow = (2 * wv + mt) * 16 + l15;
        #pragma unroll
        for (int kh = 0; kh < 2; ++kh)
            a[mt][kh] = *(const f16x8*)(xtb + prow * XROW + kh * 64 + l4 * 16);
    }

    unsigned k1[2][4], k2[2][4];
    #pragma unroll
    for (int mt = 0; mt < 2; ++mt)
        #pragma unroll
        for (int r = 0; r < 4; ++r) { k1[mt][r] = 0xFFFFFFFFu; k2[mt][r] = 0xFFFFFFFFu; }

    // free-run: 8 groups x 16 codes, no sync
    #pragma unroll
    for (int g = 0; g < 8; ++g) {
        const int r = g * 16 + l15;
        const int code = q * 128 + r;
        const int sw = (r & 7) << 4;
        f16x8 b0 = *(const f16x8*)(btb + r * 128 + ((      l4 * 16) ^ sw));
        f16x8 b1 = *(const f16x8*)(btb + r * 128 + ((64 + l4 * 16) ^ sw));
        float e2v = e2q[r];
        #pragma unroll
        for (int mt = 0; mt < 2; ++mt) {
            f32x4 acc = (f32x4){0.f, 0.f, 0.f, 0.f};
            acc = __builtin_amdgcn_mfma_f32_16x16x32_f16(a[mt][0], b0, acc, 0, 0, 0);
            acc = __builtin_amdgcn_mfma_f32_16x16x32_f16(a[mt][1], b1, acc, 0, 0, 0);
            #pragma unroll
            for (int r2 = 0; r2 < 4; ++r2) {
                float d = __fmaf_rn(-2.f, acc[r2], e2v);          // biased +512, > 0
                unsigned u = (__builtin_bit_cast(unsigned, d) & 0xFFFFFE00u) | (unsigned)code;
                k2[mt][r2] = umin_(k2[mt][r2], umax_(u, k1[mt][r2]));
                k1[mt][r2] = umin_(k1[mt][r2], u);
            }
        }
    }

    // 16-lane reduce of packed (k1, k2)
    #pragma unroll
    for (int m = 1; m < 16; m <<= 1) {
        #pragma unroll
        for (int mt = 0; mt < 2; ++mt)
            #pragma unroll
            for (int r = 0; r < 4; ++r) {
                unsigned o1 = __shfl_xor(k1[mt][r], m, 64);
                unsigned o2 = __shfl_xor(k2[mt][r], m, 64);
                k2[mt][r] = umin_(umin_(k2[mt][r], o2), umax_(k1[mt][r], o1));
                k1[mt][r] = umin_(k1[mt][r], o1);
            }
    }

    // per-pixel partial {k1, k2}; q==0 also publishes f2
    if (l15 == 0) {
        uint2* part = (uint2*)(ws + PART_OFF);
        float* f2g = (float*)(ws + F2_OFF);
        #pragma unroll
        for (int mt = 0; mt < 2; ++mt)
            #pragma unroll
            for (int r = 0; r < 4; ++r) {
                int p = wv * 32 + mt * 16 + l4 * 4 + r;
                part[(size_t)(pix0 + p) * 4 + q] = (uint2){k1[mt][r], k2[mt][r]};
                if (q == 0) f2g[pix0 + p] = f2h[0][p] + f2h[1][p];
            }
    }
}

// ---- K2: combine quarters + rigorous flag + exact recheck + apply + hist + sq ----
__global__ __launch_bounds__(256) void vq_apply(const float* __restrict__ xg,
                                                const float* __restrict__ eg,
                                                float* __restrict__ outg,
                                                char* __restrict__ ws) {
    __shared__ int idxs[PIXB];
    __shared__ unsigned char flg[PIXB];
    __shared__ float e2s[NE];
    __shared__ float xp[4][CC];
    __shared__ float wsum[4];

    const int tid  = threadIdx.x;
    const int lane = tid & 63;
    const int wv   = tid >> 6;
    const int pix0 = blockIdx.x * PIXB;
    const int bb   = pix0 >> 12;
    const size_t xbase = (size_t)bb * CHWSZ + (pix0 & 4095);

    {
        const float* e2g = (const float*)(ws + E2_OFF);
        for (int t = tid; t < NE; t += 256) e2s[t] = e2g[t];
    }
    float em = 0.f;
    {
        const float* mx = (const float*)(ws + MAXE2_OFF);
        #pragma unroll
        for (int i = 0; i < 8; ++i) em = fmaxf(em, mx[i]);
    }
    const float emax = sqrtf(em);

    if (tid < PIXB) {
        const uint2* part = (const uint2*)(ws + PART_OFF) + (size_t)(pix0 + tid) * 4;
        unsigned K1 = 0xFFFFFFFFu, K2 = 0xFFFFFFFFu;
        #pragma unroll
        for (int q = 0; q < 4; ++q) {
            uint2 pq = part[q];
            K2 = umin_(umin_(K2, pq.y), umax_(K1, pq.x));
            K1 = umin_(K1, pq.x);
        }
        float m1 = __builtin_bit_cast(float, K1 & 0xFFFFFE00u);
        float m2 = __builtin_bit_cast(float, K2 & 0xFFFFFE00u);
        float f2 = ((const float*)(ws + F2_OFF))[pix0 + tid];
        // rigorous: 2 * (2^-9*1.05 * ||f|| * ||e||max) + prefix quantum + slack
        float T = __fmaf_rn(0.00414f * sqrtf(f2), emax, 0.0335f);
        idxs[tid] = (int)(K1 & 511u);
        flg[tid] = (m2 - m1 < T) || (f2 > 380.f) ? 1 : 0;
    }
    __syncthreads();

    // per-wave exact recheck (bit-identical fp32 arithmetic): wave wv owns pixels [32wv,32wv+32)
    {
        bool f = (lane < 32) ? (flg[wv * 32 + lane] != 0) : false;
        unsigned long long mask = __ballot(f);
        while (mask) {
            int l0 = __ffsll((long long)mask) - 1;
            mask &= mask - 1;
            int p = wv * 32 + l0;
            xp[wv][lane] = xg[xbase + (size_t)lane * HWSZ + p];   // k = lane
            float rr[8];
            #pragma unroll
            for (int u = 0; u < 8; ++u) { float v = xp[wv][u]; rr[u] = __fmul_rn(v, v); }
            #pragma unroll
            for (int t2 = 1; t2 < 8; ++t2)
                #pragma unroll
                for (int u = 0; u < 8; ++u) { float v = xp[wv][t2 * 8 + u]; rr[u] = __fadd_rn(rr[u], __fmul_rn(v, v)); }
            float f2 = __fadd_rn(__fadd_rn(__fadd_rn(rr[0], rr[1]), __fadd_rn(rr[2], rr[3])),
                                 __fadd_rn(__fadd_rn(rr[4], rr[5]), __fadd_rn(rr[6], rr[7])));
            const int c0 = lane * 8;
            float dot[8];
            #pragma unroll
            for (int j = 0; j < 8; ++j) dot[j] = 0.f;
            #pragma unroll 4
            for (int k = 0; k < CC; ++k) {
                float xv = xp[wv][k];
                float4 aa = *(const float4*)(eg + k * NE + c0);
                float4 bbv = *(const float4*)(eg + k * NE + c0 + 4);
                dot[0] = __fmaf_rn(xv, aa.x, dot[0]); dot[1] = __fmaf_rn(xv, aa.y, dot[1]);
                dot[2] = __fmaf_rn(xv, aa.z, dot[2]); dot[3] = __fmaf_rn(xv, aa.w, dot[3]);
                dot[4] = __fmaf_rn(xv, bbv.x, dot[4]); dot[5] = __fmaf_rn(xv, bbv.y, dot[5]);
                dot[6] = __fmaf_rn(xv, bbv.z, dot[6]); dot[7] = __fmaf_rn(xv, bbv.w, dot[7]);
            }
            float best = 3.4e38f; int bidx = 0;
            #pragma unroll
            for (int j = 0; j < 8; ++j) {
                float d = __fadd_rn(__fmaf_rn(-2.f, dot[j], f2), e2s[c0 + j]);
                if (d < best) { best = d; bidx = c0 + j; }
            }
            #pragma unroll
            for (int m = 1; m < 64; m <<= 1) {
                float ov = __shfl_xor(best, m, 64);
                int   oi = __shfl_xor(bidx, m, 64);
                if (ov < best || (ov == best && oi < bidx)) { best = ov; bidx = oi; }
            }
            int nb = __shfl(bidx, 0, 64);
            if (lane == 0) idxs[p] = nb;
        }
    }
    __syncthreads();

    if (tid < PIXB)
        atomicAdd((unsigned int*)(ws + HIST_OFF) + (blockIdx.x & (NSTRIPE - 1)) * NE + idxs[tid], 1u);

    // apply: float4 x re-read; exact ref arithmetic out = x + (q - x); sq loss
    float sq = 0.f;
    for (int t = tid; t < 2048; t += 256) {
        int cc = t >> 5, p4 = (t & 31) << 2;
        float4 vr = *(const float4*)(xg + xbase + (size_t)cc * HWSZ + p4);
        float vv[4] = {vr.x, vr.y, vr.z, vr.w};
        float4 ov;
        float* ovp = &ov.x;
        #pragma unroll
        for (int j = 0; j < 4; ++j) {
            float qv = eg[cc * NE + idxs[p4 + j]];
            float d = __fsub_rn(qv, vv[j]);
            ovp[j] = __fadd_rn(vv[j], d);
            sq = __fmaf_rn(d, d, sq);
        }
        *(float4*)(outg + xbase + (size_t)cc * HWSZ + p4) = ov;
    }
    #pragma unroll
    for (int m = 32; m >= 1; m >>= 1) sq += __shfl_down(sq, m, 64);
    if (lane == 0) wsum[wv] = sq;
    __syncthreads();
    if (tid == 0) atomicAdd((float*)(ws + BATCH_OFF) + bb, wsum[0] + wsum[1] + wsum[2] + wsum[3]);
}

// ---- finalize: sum hist stripes, diff[32], perplexity ----
__global__ __launch_bounds__(512) void vq_fin(const char* __restrict__ ws, float* __restrict__ outg) {
    __shared__ float acc8[8];
    const int tid = threadIdx.x, lane = tid & 63, wv = tid >> 6;
    const unsigned int* h32 = (const unsigned int*)(ws + HIST_OFF);
    unsigned int h = 0;
    #pragma unroll
    for (int s = 0; s < NSTRIPE; ++s) h += h32[s * NE + tid];
    float p = (float)h * (1.f / (float)NPIX);
    float t = p * logf(p + 1e-10f);
    #pragma unroll
    for (int m = 32; m >= 1; m >>= 1) t += __shfl_down(t, m, 64);
    if (lane == 0) acc8[wv] = t;
    __syncthreads();
    if (tid < 32) outg[8388608 + tid] = ((const float*)(ws + BATCH_OFF))[tid] * (1.f / 262144.f);
    if (tid == 0) {
        float s = 0.f;
        #pragma unroll
        for (int u = 0; u < 8; ++u) s += acc8[u];
        outg[8388640] = expf(-s);
    }
}

extern "C" void kernel_launch(void* const* d_in, const int* in_sizes, int n_in,
                              void* d_out, int out_size, void* d_ws, size_t ws_size,
                              hipStream_t stream) {
    const float* xg = (const float*)d_in[0];
    const float* eg = (const float*)d_in[1];
    float* outg = (float*)d_out;
    char* ws = (char*)d_ws;
    vq_init<<<8, 512, 0, stream>>>(eg, ws);
    vq_screen<<<(NPIX / PIXB) * 4, 256, 0, stream>>>(xg, ws);
    vq_apply<<<NPIX / PIXB, 256, 0, stream>>>(xg, eg, outg, ws);
    vq_fin<<<1, 512, 0, stream>>>(ws, outg);
}

// Round 13
// 98.510 us; speedup vs baseline: 1.4432x; 1.4432x over previous
//
#include <hip/hip_runtime.h>

typedef __bf16 bf16x8 __attribute__((ext_vector_type(8)));
typedef float  f32x4  __attribute__((ext_vector_type(4)));

#define CC 64
#define HWSZ 4096
#define CHWSZ 262144
#define NE 512
#define NPIX 131072
#define PIXB 128
#define EPS_MARGIN 0.012f
#define NSTRIPE 32

#define ET_OFF 0              // 512 codes * 256 B (hi64|lo64 bf16), XOR-swizzled rows
#define E2_OFF 131072         // 512 * 4
#define HIST_OFF 133120       // 32 stripes * 512 * 4 = 65536
#define BATCH_OFF 198656      // 32 * 4
#define PART_OFF 198784       // 131072 pixels * 4 quarters * 8 B = 4194304

__device__ __forceinline__ float bf2f(unsigned short u) {
    unsigned int x = ((unsigned int)u) << 16;
    return __builtin_bit_cast(float, x);
}
__device__ __forceinline__ unsigned short f2bf(float f) {
    unsigned int x = __builtin_bit_cast(unsigned int, f);
    unsigned int r = x + 0x7fffu + ((x >> 16) & 1u);
    return (unsigned short)(r >> 16);
}
__device__ __forceinline__ void gload16(const void* g, void* l) {
    __builtin_amdgcn_global_load_lds(
        (const __attribute__((address_space(1))) unsigned int*)g,
        (__attribute__((address_space(3))) unsigned int*)l, 16, 0, 0);
}

// ---- init (8 blocks): exact e2[512]; embed^T hi/lo [code][hi64|lo64] bf16 PRE-SWIZZLED ----
__global__ __launch_bounds__(512) void vq_init(const float* __restrict__ eg, char* __restrict__ ws) {
    const int tid = threadIdx.x, blk = blockIdx.x;
    if (tid < 64) {
        int n = blk * 64 + tid;
        float s = 0.f;
        #pragma unroll 8
        for (int k = 0; k < CC; ++k) { float v = eg[k * NE + n]; s = __fadd_rn(s, __fmul_rn(v, v)); }
        ((float*)(ws + E2_OFF))[n] = s;
    }
    char* et = ws + ET_OFF;
    #pragma unroll
    for (int it = 0; it < 8; ++it) {
        int idx = blk * 4096 + it * 512 + tid;   // global word index
        int n = idx >> 6, w = idx & 63;
        int k = (w & 31) << 1;
        float v0 = eg[k * NE + n], v1 = eg[(k + 1) * NE + n];
        unsigned short c0, c1;
        if (w < 32) { c0 = f2bf(v0); c1 = f2bf(v1); }
        else {
            unsigned short h0 = f2bf(v0), h1 = f2bf(v1);
            c0 = f2bf(__fsub_rn(v0, bf2f(h0)));
            c1 = f2bf(__fsub_rn(v1, bf2f(h1)));
        }
        int b = (n * 256 + w * 4) ^ ((n & 15) << 4);   // row-local XOR swizzle (matches reader)
        *(unsigned int*)(et + b) = (unsigned int)c0 | ((unsigned int)c1 << 16);
    }
    unsigned int* h32 = (unsigned int*)(ws + HIST_OFF);
    for (int i = blk * 2048 + tid; i < (blk + 1) * 2048; i += 512) h32[i] = 0u;
    if (blk == 0 && tid < 32) ((float*)(ws + BATCH_OFF))[tid] = 0.f;
}

// ---- K1: split-bf16 screen, NO x-LDS-tile (A direct global->reg), B quarter in LDS,
// one barrier, free-run. 33KB LDS -> 4 blocks/CU; 2 m-tiles/wave. ----
__global__ __launch_bounds__(256) void vq_screen(const float* __restrict__ xg,
                                                 char* __restrict__ ws) {
    __shared__ __align__(16) char btb[32768];   // 128 codes x 256 B (hi|lo), swizzled
    __shared__ float e2q[128];

    const int tid  = threadIdx.x;
    const int lane = tid & 63;
    const int wv   = tid >> 6;
    const int l15  = lane & 15;
    const int l4   = lane >> 4;
    const int blk  = blockIdx.x;
    const int tile = blk >> 2;
    const int q    = blk & 3;
    const int pix0 = tile * PIXB;
    const int bb   = pix0 >> 12;
    const size_t xbase = (size_t)bb * CHWSZ + (pix0 & 4095);

    // stage B quarter (pre-swizzled bytes; linear 1:1 copy): 32KB = 8 x (256thr x 16B)
    #pragma unroll
    for (int i = 0; i < 8; ++i)
        gload16(ws + ET_OFF + (size_t)q * 32768 + i * 4096 + tid * 16, &btb[i * 4096 + tid * 16]);
    if (tid < 128) e2q[tid] = ((const float*)(ws + E2_OFF))[q * 128 + tid];

    // A fragments direct from global: wave owns pixels [32wv,32wv+32); 16-lane groups read
    // 16 consecutive pixels at fixed k -> 64B segments (cache-line efficient).
    bf16x8 ah[2][2], al[2][2];
    #pragma unroll
    for (int mt = 0; mt < 2; ++mt) {
        const int p = (2 * wv + mt) * 16 + l15;
        #pragma unroll
        for (int kh = 0; kh < 2; ++kh) {
            float v[8];
            #pragma unroll
            for (int e = 0; e < 8; ++e)
                v[e] = xg[xbase + (size_t)(kh * 32 + l4 * 8 + e) * HWSZ + p];
            union { bf16x8 vec; unsigned short s[8]; } uh, ul;
            #pragma unroll
            for (int e = 0; e < 8; ++e) {
                unsigned short hb = f2bf(v[e]);
                uh.s[e] = hb;
                ul.s[e] = f2bf(__fsub_rn(v[e], bf2f(hb)));
            }
            ah[mt][kh] = uh.vec;
            al[mt][kh] = ul.vec;
        }
    }
    asm volatile("s_waitcnt vmcnt(0) lgkmcnt(0)" ::: "memory");
    __builtin_amdgcn_sched_barrier(0);
    __builtin_amdgcn_s_barrier();          // the ONLY barrier: btb + e2q resident
    __builtin_amdgcn_sched_barrier(0);

    float minv[2][4], min2v[2][4];
    int   mini[2][4];
    #pragma unroll
    for (int mt = 0; mt < 2; ++mt)
        #pragma unroll
        for (int r = 0; r < 4; ++r) { minv[mt][r] = 3.4e38f; min2v[mt][r] = 3.4e38f; mini[mt][r] = 0; }

    // free-run: 8 groups x 16 codes, fully unrolled, no sync
    #pragma unroll
    for (int g = 0; g < 8; ++g) {
        const int r = g * 16 + l15;
        const int code = q * 128 + r;
        const int ro = r * 256 + l4 * 16;
        const int sw2 = (r & 15) << 4;
        bf16x8 bh0 = *(const bf16x8*)(btb + ((ro +   0) ^ sw2));
        bf16x8 bh1 = *(const bf16x8*)(btb + ((ro +  64) ^ sw2));
        bf16x8 bl0 = *(const bf16x8*)(btb + ((ro + 128) ^ sw2));
        bf16x8 bl1 = *(const bf16x8*)(btb + ((ro + 192) ^ sw2));
        float e2v = e2q[r];
        #pragma unroll
        for (int mt = 0; mt < 2; ++mt) {
            f32x4 acc = (f32x4){0.f, 0.f, 0.f, 0.f};
            acc = __builtin_amdgcn_mfma_f32_16x16x32_bf16(ah[mt][0], bh0, acc, 0, 0, 0);
            acc = __builtin_amdgcn_mfma_f32_16x16x32_bf16(ah[mt][1], bh1, acc, 0, 0, 0);
            acc = __builtin_amdgcn_mfma_f32_16x16x32_bf16(ah[mt][0], bl0, acc, 0, 0, 0);
            acc = __builtin_amdgcn_mfma_f32_16x16x32_bf16(ah[mt][1], bl1, acc, 0, 0, 0);
            acc = __builtin_amdgcn_mfma_f32_16x16x32_bf16(al[mt][0], bh0, acc, 0, 0, 0);
            acc = __builtin_amdgcn_mfma_f32_16x16x32_bf16(al[mt][1], bh1, acc, 0, 0, 0);
            #pragma unroll
            for (int r2 = 0; r2 < 4; ++r2) {
                float d = __fmaf_rn(-2.f, acc[r2], e2v);
                bool lt = d < minv[mt][r2];
                min2v[mt][r2] = fminf(min2v[mt][r2], fmaxf(d, minv[mt][r2]));
                minv[mt][r2] = lt ? d : minv[mt][r2];
                mini[mt][r2] = lt ? code : mini[mt][r2];
            }
        }
    }

    // 16-lane argmin reduce with second-min + first-index tie-break
    #pragma unroll
    for (int m = 1; m < 16; m <<= 1) {
        #pragma unroll
        for (int mt = 0; mt < 2; ++mt)
            #pragma unroll
            for (int r = 0; r < 4; ++r) {
                float ov  = __shfl_xor(minv[mt][r], m, 64);
                int   oi  = __shfl_xor(mini[mt][r], m, 64);
                float ov2 = __shfl_xor(min2v[mt][r], m, 64);
                bool sel = (ov < minv[mt][r]) || (ov == minv[mt][r] && oi < mini[mt][r]);
                float big = sel ? minv[mt][r] : ov;
                min2v[mt][r] = fminf(fminf(min2v[mt][r], ov2), big);
                minv[mt][r] = sel ? ov : minv[mt][r];
                mini[mt][r] = sel ? oi : mini[mt][r];
            }
    }

    // packed partial per pixel: {hi: min f32 bits, lo: idx u16 | margin f16 << 16}
    if (l15 == 0) {
        uint2* part = (uint2*)(ws + PART_OFF);
        #pragma unroll
        for (int mt = 0; mt < 2; ++mt)
            #pragma unroll
            for (int r = 0; r < 4; ++r) {
                int p = wv * 32 + mt * 16 + l4 * 4 + r;
                float margin = min2v[mt][r] - minv[mt][r];
                _Float16 mh = (_Float16)margin;
                unsigned int lo = (unsigned int)mini[mt][r]
                                | ((unsigned int)__builtin_bit_cast(unsigned short, mh) << 16);
                unsigned int hi = __builtin_bit_cast(unsigned int, minv[mt][r]);
                part[(size_t)(pix0 + p) * 4 + q] = (uint2){lo, hi};
            }
    }
}

// ---- K2: combine quarters + exact recheck + apply + hist + sq (r11-proven) ----
__global__ __launch_bounds__(256) void vq_apply(const float* __restrict__ xg,
                                                const float* __restrict__ eg,
                                                float* __restrict__ outg,
                                                char* __restrict__ ws) {
    __shared__ int idxs[PIXB];
    __shared__ unsigned char flg[PIXB];
    __shared__ float e2s[NE];
    __shared__ float xp[4][CC];
    __shared__ float wsum[4];

    const int tid  = threadIdx.x;
    const int lane = tid & 63;
    const int wv   = tid >> 6;
    const int pix0 = blockIdx.x * PIXB;
    const int bb   = pix0 >> 12;
    const size_t xbase = (size_t)bb * CHWSZ + (pix0 & 4095);

    {
        const float* e2g = (const float*)(ws + E2_OFF);
        for (int t = tid; t < NE; t += 256) e2s[t] = e2g[t];
    }

    // combine 4 quarters per pixel
    if (tid < PIXB) {
        const uint2* part = (const uint2*)(ws + PART_OFF) + (size_t)(pix0 + tid) * 4;
        float g1 = 3.4e38f, g2 = 3.4e38f;
        int gi = 0;
        #pragma unroll
        for (int q = 0; q < 4; ++q) {
            uint2 pa = part[q];
            float m = __builtin_bit_cast(float, pa.y);
            int idx = (int)(pa.x & 0xffffu);
            _Float16 mh = __builtin_bit_cast(_Float16, (unsigned short)(pa.x >> 16));
            float m2 = m + (float)mh;
            if (m < g1) { g2 = fminf(g1, m2); g1 = m; gi = idx; }
            else        { g2 = fminf(g2, m); }
        }
        idxs[tid] = gi;
        flg[tid] = (g2 - g1 < EPS_MARGIN) ? 1 : 0;
    }
    __syncthreads();

    // per-wave exact recheck (bit-identical fp32 arithmetic): wave wv owns pixels [32wv,32wv+32)
    {
        bool f = (lane < 32) ? (flg[wv * 32 + lane] != 0) : false;
        unsigned long long mask = __ballot(f);
        while (mask) {
            int l0 = __ffsll((long long)mask) - 1;
            mask &= mask - 1;
            int p = wv * 32 + l0;
            xp[wv][lane] = xg[xbase + (size_t)lane * HWSZ + p];   // k = lane
            float rr[8];
            #pragma unroll
            for (int u = 0; u < 8; ++u) { float v = xp[wv][u]; rr[u] = __fmul_rn(v, v); }
            #pragma unroll
            for (int t2 = 1; t2 < 8; ++t2)
                #pragma unroll
                for (int u = 0; u < 8; ++u) { float v = xp[wv][t2 * 8 + u]; rr[u] = __fadd_rn(rr[u], __fmul_rn(v, v)); }
            float f2 = __fadd_rn(__fadd_rn(__fadd_rn(rr[0], rr[1]), __fadd_rn(rr[2], rr[3])),
                                 __fadd_rn(__fadd_rn(rr[4], rr[5]), __fadd_rn(rr[6], rr[7])));
            const int c0 = lane * 8;
            float dot[8];
            #pragma unroll
            for (int j = 0; j < 8; ++j) dot[j] = 0.f;
            #pragma unroll 4
            for (int k = 0; k < CC; ++k) {
                float xv = xp[wv][k];
                float4 aa = *(const float4*)(eg + k * NE + c0);
                float4 bbv = *(const float4*)(eg + k * NE + c0 + 4);
                dot[0] = __fmaf_rn(xv, aa.x, dot[0]); dot[1] = __fmaf_rn(xv, aa.y, dot[1]);
                dot[2] = __fmaf_rn(xv, aa.z, dot[2]); dot[3] = __fmaf_rn(xv, aa.w, dot[3]);
                dot[4] = __fmaf_rn(xv, bbv.x, dot[4]); dot[5] = __fmaf_rn(xv, bbv.y, dot[5]);
                dot[6] = __fmaf_rn(xv, bbv.z, dot[6]); dot[7] = __fmaf_rn(xv, bbv.w, dot[7]);
            }
            float best = 3.4e38f; int bidx = 0;
            #pragma unroll
            for (int j = 0; j < 8; ++j) {
                float d = __fadd_rn(__fmaf_rn(-2.f, dot[j], f2), e2s[c0 + j]);
                if (d < best) { best = d; bidx = c0 + j; }
            }
            #pragma unroll
            for (int m = 1; m < 64; m <<= 1) {
                float ov = __shfl_xor(best, m, 64);
                int   oi = __shfl_xor(bidx, m, 64);
                if (ov < best || (ov == best && oi < bidx)) { best = ov; bidx = oi; }
            }
            int nb = __shfl(bidx, 0, 64);
            if (lane == 0) idxs[p] = nb;
        }
    }
    __syncthreads();

    if (tid < PIXB)
        atomicAdd((unsigned int*)(ws + HIST_OFF) + (blockIdx.x & (NSTRIPE - 1)) * NE + idxs[tid], 1u);

    // apply: float4 x re-read; exact ref arithmetic out = x + (q - x); sq loss
    float sq = 0.f;
    for (int t = tid; t < 2048; t += 256) {
        int cc = t >> 5, p4 = (t & 31) << 2;
        float4 vr = *(const float4*)(xg + xbase + (size_t)cc * HWSZ + p4);
        float vv[4] = {vr.x, vr.y, vr.z, vr.w};
        float4 ov;
        float* ovp = &ov.x;
        #pragma unroll
        for (int j = 0; j < 4; ++j) {
            float qv = eg[cc * NE + idxs[p4 + j]];
            float d = __fsub_rn(qv, vv[j]);
            ovp[j] = __fadd_rn(vv[j], d);
            sq = __fmaf_rn(d, d, sq);
        }
        *(float4*)(outg + xbase + (size_t)cc * HWSZ + p4) = ov;
    }
    #pragma unroll
    for (int m = 32; m >= 1; m >>= 1) sq += __shfl_down(sq, m, 64);
    if (lane == 0) wsum[wv] = sq;
    __syncthreads();
    if (tid == 0) atomicAdd((float*)(ws + BATCH_OFF) + bb, wsum[0] + wsum[1] + wsum[2] + wsum[3]);
}

// ---- finalize: sum hist stripes, diff[32], perplexity ----
__global__ __launch_bounds__(512) void vq_fin(const char* __restrict__ ws, float* __restrict__ outg) {
    __shared__ float acc8[8];
    const int tid = threadIdx.x, lane = tid & 63, wv = tid >> 6;
    const unsigned int* h32 = (const unsigned int*)(ws + HIST_OFF);
    unsigned int h = 0;
    #pragma unroll
    for (int s = 0; s < NSTRIPE; ++s) h += h32[s * NE + tid];
    float p = (float)h * (1.f / (float)NPIX);
    float t = p * logf(p + 1e-10f);
    #pragma unroll
    for (int m = 32; m >= 1; m >>= 1) t += __shfl_down(t, m, 64);
    if (lane == 0) acc8[wv] = t;
    __syncthreads();
    if (tid < 32) outg[8388608 + tid] = ((const float*)(ws + BATCH_OFF))[tid] * (1.f / 262144.f);
    if (tid == 0) {
        float s = 0.f;
        #pragma unroll
        for (int u = 0; u < 8; ++u) s += acc8[u];
        outg[8388640] = expf(-s);
    }
}

extern "C" void kernel_launch(void* const* d_in, const int* in_sizes, int n_in,
                              void* d_out, int out_size, void* d_ws, size_t ws_size,
                              hipStream_t stream) {
    const float* xg = (const float*)d_in[0];
    const float* eg = (const float*)d_in[1];
    float* outg = (float*)d_out;
    char* ws = (char*)d_ws;
    vq_init<<<8, 512, 0, stream>>>(eg, ws);
    vq_screen<<<(NPIX / PIXB) * 4, 256, 0, stream>>>(xg, ws);
    vq_apply<<<NPIX / PIXB, 256, 0, stream>>>(xg, eg, outg, ws);
    vq_fin<<<1, 512, 0, stream>>>(ws, outg);
}

// Round 14
// 86.976 us; speedup vs baseline: 1.6346x; 1.1326x over previous
//
#include <hip/hip_runtime.h>

typedef __bf16 bf16x8 __attribute__((ext_vector_type(8)));
typedef float  f32x4  __attribute__((ext_vector_type(4)));

#define CC 64
#define HWSZ 4096
#define CHWSZ 262144
#define NE 512
#define NPIX 131072
#define PIXB 128
#define FLAG_T 0.024f         // 0.012 split-err + 0.0078 mask quantum + slack
#define NSTRIPE 32

#define ET_OFF 0              // 512 codes * 256 B (hi64|lo64 bf16), XOR-swizzled rows
#define E2_OFF 131072         // 512 * 4
#define HIST_OFF 133120       // 32 stripes * 512 * 4 = 65536
#define BATCH_OFF 198656      // 32 * 4
#define PART_OFF 198784       // 131072 pixels * 4 quarters * 8 B = 4194304

__device__ __forceinline__ float bf2f(unsigned short u) {
    unsigned int x = ((unsigned int)u) << 16;
    return __builtin_bit_cast(float, x);
}
__device__ __forceinline__ unsigned short f2bf(float f) {
    unsigned int x = __builtin_bit_cast(unsigned int, f);
    unsigned int r = x + 0x7fffu + ((x >> 16) & 1u);
    return (unsigned short)(r >> 16);
}
__device__ __forceinline__ unsigned umin_(unsigned a, unsigned b) { return a < b ? a : b; }
__device__ __forceinline__ unsigned umax_(unsigned a, unsigned b) { return a > b ? a : b; }
__device__ __forceinline__ void gload16(const void* g, void* l) {
    __builtin_amdgcn_global_load_lds(
        (const __attribute__((address_space(1))) unsigned int*)g,
        (__attribute__((address_space(3))) unsigned int*)l, 16, 0, 0);
}

// ---- init (8 blocks): exact e2[512]; embed^T hi/lo [code][hi64|lo64] bf16 PRE-SWIZZLED ----
__global__ __launch_bounds__(512) void vq_init(const float* __restrict__ eg, char* __restrict__ ws) {
    const int tid = threadIdx.x, blk = blockIdx.x;
    if (tid < 64) {
        int n = blk * 64 + tid;
        float s = 0.f;
        #pragma unroll 8
        for (int k = 0; k < CC; ++k) { float v = eg[k * NE + n]; s = __fadd_rn(s, __fmul_rn(v, v)); }
        ((float*)(ws + E2_OFF))[n] = s;
    }
    char* et = ws + ET_OFF;
    #pragma unroll
    for (int it = 0; it < 8; ++it) {
        int idx = blk * 4096 + it * 512 + tid;   // global word index
        int n = idx >> 6, w = idx & 63;
        int k = (w & 31) << 1;
        float v0 = eg[k * NE + n], v1 = eg[(k + 1) * NE + n];
        unsigned short c0, c1;
        if (w < 32) { c0 = f2bf(v0); c1 = f2bf(v1); }
        else {
            unsigned short h0 = f2bf(v0), h1 = f2bf(v1);
            c0 = f2bf(__fsub_rn(v0, bf2f(h0)));
            c1 = f2bf(__fsub_rn(v1, bf2f(h1)));
        }
        int b = (n * 256 + w * 4) ^ ((n & 15) << 4);   // row-local XOR swizzle (matches reader)
        *(unsigned int*)(et + b) = (unsigned int)c0 | ((unsigned int)c1 << 16);
    }
    unsigned int* h32 = (unsigned int*)(ws + HIST_OFF);
    for (int i = blk * 2048 + tid; i < (blk + 1) * 2048; i += 512) h32[i] = 0u;
    if (blk == 0 && tid < 32) ((float*)(ws + BATCH_OFF))[tid] = 0.f;
}

// ---- K1: split-bf16 screen, A direct global->reg (native cvt_pk splits), B quarter in
// LDS, packed-key (7-bit code) argmin, one barrier, free-run. ----
__global__ __launch_bounds__(256) void vq_screen(const float* __restrict__ xg,
                                                 char* __restrict__ ws) {
    __shared__ __align__(16) char btb[32768];   // 128 codes x 256 B (hi|lo), swizzled
    __shared__ float e2q[128];

    const int tid  = threadIdx.x;
    const int lane = tid & 63;
    const int wv   = tid >> 6;
    const int l15  = lane & 15;
    const int l4   = lane >> 4;
    const int blk  = blockIdx.x;
    const int tile = blk >> 2;
    const int q    = blk & 3;
    const int pix0 = tile * PIXB;
    const int bb   = pix0 >> 12;
    const size_t xbase = (size_t)bb * CHWSZ + (pix0 & 4095);

    // stage B quarter (pre-swizzled bytes; linear 1:1 copy): 32KB = 8 x (256thr x 16B)
    #pragma unroll
    for (int i = 0; i < 8; ++i)
        gload16(ws + ET_OFF + (size_t)q * 32768 + i * 4096 + tid * 16, &btb[i * 4096 + tid * 16]);
    if (tid < 128) e2q[tid] = ((const float*)(ws + E2_OFF))[q * 128 + tid] + 512.f;   // biased

    // A fragments direct from global; native bf16 casts (compiler emits v_cvt_pk_bf16_f32)
    bf16x8 ah[2][2], al[2][2];
    #pragma unroll
    for (int mt = 0; mt < 2; ++mt) {
        const int p = (2 * wv + mt) * 16 + l15;
        #pragma unroll
        for (int kh = 0; kh < 2; ++kh) {
            float v[8];
            #pragma unroll
            for (int e = 0; e < 8; ++e)
                v[e] = xg[xbase + (size_t)(kh * 32 + l4 * 8 + e) * HWSZ + p];
            bf16x8 hv, lv;
            #pragma unroll
            for (int e = 0; e < 8; ++e) {
                __bf16 hb = (__bf16)v[e];
                hv[e] = hb;
                lv[e] = (__bf16)__fsub_rn(v[e], (float)hb);
            }
            ah[mt][kh] = hv;
            al[mt][kh] = lv;
        }
    }
    asm volatile("s_waitcnt vmcnt(0) lgkmcnt(0)" ::: "memory");
    __builtin_amdgcn_sched_barrier(0);
    __builtin_amdgcn_s_barrier();          // the ONLY barrier: btb + e2q resident
    __builtin_amdgcn_sched_barrier(0);

    unsigned k1[2][4], k2[2][4];
    #pragma unroll
    for (int mt = 0; mt < 2; ++mt)
        #pragma unroll
        for (int r = 0; r < 4; ++r) { k1[mt][r] = 0xFFFFFFFFu; k2[mt][r] = 0xFFFFFFFFu; }

    // free-run: 8 groups x 16 codes, fully unrolled, no sync
    #pragma unroll
    for (int g = 0; g < 8; ++g) {
        const int r = g * 16 + l15;           // quarter-local code 0..127
        const int ro = r * 256 + l4 * 16;
        const int sw2 = (r & 15) << 4;
        bf16x8 bh0 = *(const bf16x8*)(btb + ((ro +   0) ^ sw2));
        bf16x8 bh1 = *(const bf16x8*)(btb + ((ro +  64) ^ sw2));
        bf16x8 bl0 = *(const bf16x8*)(btb + ((ro + 128) ^ sw2));
        bf16x8 bl1 = *(const bf16x8*)(btb + ((ro + 192) ^ sw2));
        float e2v = e2q[r];
        #pragma unroll
        for (int mt = 0; mt < 2; ++mt) {
            f32x4 acc = (f32x4){0.f, 0.f, 0.f, 0.f};
            acc = __builtin_amdgcn_mfma_f32_16x16x32_bf16(ah[mt][0], bh0, acc, 0, 0, 0);
            acc = __builtin_amdgcn_mfma_f32_16x16x32_bf16(ah[mt][1], bh1, acc, 0, 0, 0);
            acc = __builtin_amdgcn_mfma_f32_16x16x32_bf16(ah[mt][0], bl0, acc, 0, 0, 0);
            acc = __builtin_amdgcn_mfma_f32_16x16x32_bf16(ah[mt][1], bl1, acc, 0, 0, 0);
            acc = __builtin_amdgcn_mfma_f32_16x16x32_bf16(al[mt][0], bh0, acc, 0, 0, 0);
            acc = __builtin_amdgcn_mfma_f32_16x16x32_bf16(al[mt][1], bh1, acc, 0, 0, 0);
            #pragma unroll
            for (int r2 = 0; r2 < 4; ++r2) {
                float d = __fmaf_rn(-2.f, acc[r2], e2v);       // biased +512, > 0
                unsigned u = (__builtin_bit_cast(unsigned, d) & 0xFFFFFF80u) | (unsigned)r;
                k2[mt][r2] = umin_(k2[mt][r2], umax_(u, k1[mt][r2]));
                k1[mt][r2] = umin_(k1[mt][r2], u);
            }
        }
    }

    // 16-lane reduce of packed (k1, k2)
    #pragma unroll
    for (int m = 1; m < 16; m <<= 1) {
        #pragma unroll
        for (int mt = 0; mt < 2; ++mt)
            #pragma unroll
            for (int r = 0; r < 4; ++r) {
                unsigned o1 = __shfl_xor(k1[mt][r], m, 64);
                unsigned o2 = __shfl_xor(k2[mt][r], m, 64);
                k2[mt][r] = umin_(umin_(k2[mt][r], o2), umax_(k1[mt][r], o1));
                k1[mt][r] = umin_(k1[mt][r], o1);
            }
    }

    // per-pixel partial {k1, k2}
    if (l15 == 0) {
        uint2* part = (uint2*)(ws + PART_OFF);
        #pragma unroll
        for (int mt = 0; mt < 2; ++mt)
            #pragma unroll
            for (int r = 0; r < 4; ++r) {
                int p = wv * 32 + mt * 16 + l4 * 4 + r;
                part[(size_t)(pix0 + p) * 4 + q] = (uint2){k1[mt][r], k2[mt][r]};
            }
    }
}

// ---- K2: combine quarters + flag + exact recheck + apply + hist + sq ----
__global__ __launch_bounds__(256) void vq_apply(const float* __restrict__ xg,
                                                const float* __restrict__ eg,
                                                float* __restrict__ outg,
                                                char* __restrict__ ws) {
    __shared__ int idxs[PIXB];
    __shared__ unsigned char flg[PIXB];
    __shared__ float e2s[NE];
    __shared__ float xp[4][CC];
    __shared__ float wsum[4];

    const int tid  = threadIdx.x;
    const int lane = tid & 63;
    const int wv   = tid >> 6;
    const int pix0 = blockIdx.x * PIXB;
    const int bb   = pix0 >> 12;
    const size_t xbase = (size_t)bb * CHWSZ + (pix0 & 4095);

    {
        const float* e2g = (const float*)(ws + E2_OFF);
        for (int t = tid; t < NE; t += 256) e2s[t] = e2g[t];
    }

    // combine 4 quarters per pixel (u32 packed keys; cross-quarter ties get flagged)
    if (tid < PIXB) {
        const uint2* part = (const uint2*)(ws + PART_OFF) + (size_t)(pix0 + tid) * 4;
        unsigned K1 = 0xFFFFFFFFu, K2 = 0xFFFFFFFFu;
        int gq = 0;
        #pragma unroll
        for (int q = 0; q < 4; ++q) {
            uint2 pq = part[q];
            K2 = umin_(umin_(K2, pq.y), umax_(K1, pq.x));
            if (pq.x < K1) { K1 = pq.x; gq = q; }
        }
        float m1 = __builtin_bit_cast(float, K1 & 0xFFFFFF80u);
        float m2 = __builtin_bit_cast(float, K2 & 0xFFFFFF80u);
        idxs[tid] = gq * 128 + (int)(K1 & 127u);
        flg[tid] = (m2 - m1 < FLAG_T) ? 1 : 0;
    }
    __syncthreads();

    // per-wave exact recheck (bit-identical fp32 arithmetic): wave wv owns pixels [32wv,32wv+32)
    {
        bool f = (lane < 32) ? (flg[wv * 32 + lane] != 0) : false;
        unsigned long long mask = __ballot(f);
        while (mask) {
            int l0 = __ffsll((long long)mask) - 1;
            mask &= mask - 1;
            int p = wv * 32 + l0;
            xp[wv][lane] = xg[xbase + (size_t)lane * HWSZ + p];   // k = lane
            float rr[8];
            #pragma unroll
            for (int u = 0; u < 8; ++u) { float v = xp[wv][u]; rr[u] = __fmul_rn(v, v); }
            #pragma unroll
            for (int t2 = 1; t2 < 8; ++t2)
                #pragma unroll
                for (int u = 0; u < 8; ++u) { float v = xp[wv][t2 * 8 + u]; rr[u] = __fadd_rn(rr[u], __fmul_rn(v, v)); }
            float f2 = __fadd_rn(__fadd_rn(__fadd_rn(rr[0], rr[1]), __fadd_rn(rr[2], rr[3])),
                                 __fadd_rn(__fadd_rn(rr[4], rr[5]), __fadd_rn(rr[6], rr[7])));
            const int c0 = lane * 8;
            float dot[8];
            #pragma unroll
            for (int j = 0; j < 8; ++j) dot[j] = 0.f;
            #pragma unroll 4
            for (int k = 0; k < CC; ++k) {
                float xv = xp[wv][k];
                float4 aa = *(const float4*)(eg + k * NE + c0);
                float4 bbv = *(const float4*)(eg + k * NE + c0 + 4);
                dot[0] = __fmaf_rn(xv, aa.x, dot[0]); dot[1] = __fmaf_rn(xv, aa.y, dot[1]);
                dot[2] = __fmaf_rn(xv, aa.z, dot[2]); dot[3] = __fmaf_rn(xv, aa.w, dot[3]);
                dot[4] = __fmaf_rn(xv, bbv.x, dot[4]); dot[5] = __fmaf_rn(xv, bbv.y, dot[5]);
                dot[6] = __fmaf_rn(xv, bbv.z, dot[6]); dot[7] = __fmaf_rn(xv, bbv.w, dot[7]);
            }
            float best = 3.4e38f; int bidx = 0;
            #pragma unroll
            for (int j = 0; j < 8; ++j) {
                float d = __fadd_rn(__fmaf_rn(-2.f, dot[j], f2), e2s[c0 + j]);
                if (d < best) { best = d; bidx = c0 + j; }
            }
            #pragma unroll
            for (int m = 1; m < 64; m <<= 1) {
                float ov = __shfl_xor(best, m, 64);
                int   oi = __shfl_xor(bidx, m, 64);
                if (ov < best || (ov == best && oi < bidx)) { best = ov; bidx = oi; }
            }
            int nb = __shfl(bidx, 0, 64);
            if (lane == 0) idxs[p] = nb;
        }
    }
    __syncthreads();

    if (tid < PIXB)
        atomicAdd((unsigned int*)(ws + HIST_OFF) + (blockIdx.x & (NSTRIPE - 1)) * NE + idxs[tid], 1u);

    // apply: float4 x re-read; exact ref arithmetic out = x + (q - x); sq loss
    float sq = 0.f;
    for (int t = tid; t < 2048; t += 256) {
        int cc = t >> 5, p4 = (t & 31) << 2;
        float4 vr = *(const float4*)(xg + xbase + (size_t)cc * HWSZ + p4);
        float vv[4] = {vr.x, vr.y, vr.z, vr.w};
        float4 ov;
        float* ovp = &ov.x;
        #pragma unroll
        for (int j = 0; j < 4; ++j) {
            float qv = eg[cc * NE + idxs[p4 + j]];
            float d = __fsub_rn(qv, vv[j]);
            ovp[j] = __fadd_rn(vv[j], d);
            sq = __fmaf_rn(d, d, sq);
        }
        *(float4*)(outg + xbase + (size_t)cc * HWSZ + p4) = ov;
    }
    #pragma unroll
    for (int m = 32; m >= 1; m >>= 1) sq += __shfl_down(sq, m, 64);
    if (lane == 0) wsum[wv] = sq;
    __syncthreads();
    if (tid == 0) atomicAdd((float*)(ws + BATCH_OFF) + bb, wsum[0] + wsum[1] + wsum[2] + wsum[3]);
}

// ---- finalize: sum hist stripes, diff[32], perplexity ----
__global__ __launch_bounds__(512) void vq_fin(const char* __restrict__ ws, float* __restrict__ outg) {
    __shared__ float acc8[8];
    const int tid = threadIdx.x, lane = tid & 63, wv = tid >> 6;
    const unsigned int* h32 = (const unsigned int*)(ws + HIST_OFF);
    unsigned int h = 0;
    #pragma unroll
    for (int s = 0; s < NSTRIPE; ++s) h += h32[s * NE + tid];
    float p = (float)h * (1.f / (float)NPIX);
    float t = p * logf(p + 1e-10f);
    #pragma unroll
    for (int m = 32; m >= 1; m >>= 1) t += __shfl_down(t, m, 64);
    if (lane == 0) acc8[wv] = t;
    __syncthreads();
    if (tid < 32) outg[8388608 + tid] = ((const float*)(ws + BATCH_OFF))[tid] * (1.f / 262144.f);
    if (tid == 0) {
        float s = 0.f;
        #pragma unroll
        for (int u = 0; u < 8; ++u) s += acc8[u];
        outg[8388640] = expf(-s);
    }
}

extern "C" void kernel_launch(void* const* d_in, const int* in_sizes, int n_in,
                              void* d_out, int out_size, void* d_ws, size_t ws_size,
                              hipStream_t stream) {
    const float* xg = (const float*)d_in[0];
    const float* eg = (const float*)d_in[1];
    float* outg = (float*)d_out;
    char* ws = (char*)d_ws;
    vq_init<<<8, 512, 0, stream>>>(eg, ws);
    vq_screen<<<(NPIX / PIXB) * 4, 256, 0, stream>>>(xg, ws);
    vq_apply<<<NPIX / PIXB, 256, 0, stream>>>(xg, eg, outg, ws);
    vq_fin<<<1, 512, 0, stream>>>(ws, outg);
}